// Round 1
// baseline (443.527 us; speedup 1.0000x reference)
//
#include <hip/hip_runtime.h>
#include <hip/hip_bf16.h>

// GraphEncoder: the entire edge/message/update pipeline in the reference is
// dead code (update() output is discarded; h is only ever scaled per-node by
// pooling scores). Live computation:
//   a_n = relu(x_n @ W1 + b1)                       (128-dim, per node)
//   d_{n,k} = a_n . (W2 @ w_k/||w_k||) + b2.(w_k/||w_k||)   k=0..2
//   cascade: s = tanh(c * d_k) on alive nodes, top-k per graph (1024/512/256),
//            c *= s on survivors
//   out_g = ((sum_sel c_n a_n) @ W2 + (sum c_n) b2) / 256

#define NPG    2048
#define NGRAPH 32

__global__ __launch_bounds__(256) void k0_prep(
    const float* __restrict__ pw,   // pool_w [3][128]
    const float* __restrict__ W2,   // [128][128]
    const float* __restrict__ b2,   // [128]
    float* __restrict__ vout,       // [3][128]
    float* __restrict__ cout)       // [4]
{
    __shared__ float swn[384];
    __shared__ float snorm[3];
    int t = threadIdx.x;
    int lane = t & 63, wv = t >> 6;
    if (wv < 3) {
        float w0 = pw[wv * 128 + lane];
        float w1 = pw[wv * 128 + 64 + lane];
        float p = w0 * w0 + w1 * w1;
        #pragma unroll
        for (int s = 32; s; s >>= 1) p += __shfl_xor(p, s);
        if (lane == 0) snorm[wv] = sqrtf(p);
    }
    __syncthreads();
    for (int i = t; i < 384; i += 256) swn[i] = pw[i] / snorm[i >> 7];
    __syncthreads();
    // 3*129 dot-products of length 128 (j==128 row is b2 -> c_k)
    for (int task = wv; task < 3 * 129; task += 4) {
        int k = task / 129, j = task % 129;
        const float* row = (j < 128) ? (W2 + j * 128) : b2;
        float p = row[lane] * swn[k * 128 + lane]
                + row[lane + 64] * swn[k * 128 + lane + 64];
        #pragma unroll
        for (int s = 32; s; s >>= 1) p += __shfl_xor(p, s);
        if (lane == 0) {
            if (j < 128) vout[k * 128 + j] = p;
            else cout[k] = p;
        }
    }
}

__global__ __launch_bounds__(256) void k1_dots(
    const float* __restrict__ x,    // [65536][16]
    const float* __restrict__ W1,   // [16][128]
    const float* __restrict__ b1,   // [128]
    const float* __restrict__ vws,  // [3][128]
    const float* __restrict__ cws,  // [4]
    float4* __restrict__ d4)        // [65536] {d0,d1,d2,_}
{
    __shared__ float sW1[2048];
    __shared__ float sb1[128];
    __shared__ float sv[384];
    __shared__ float sc[4];
    int t = threadIdx.x;
    for (int i = t; i < 2048; i += 256) sW1[i] = W1[i];
    if (t < 128) sb1[t] = b1[t];
    for (int i = t; i < 384; i += 256) sv[i] = vws[i];
    if (t < 4) sc[t] = cws[t];
    __syncthreads();
    int lane = t & 63, wv = t >> 6;
    int base = blockIdx.x * 64 + wv * 16;   // wave processes 16 nodes
    for (int u = 0; u < 16; ++u) {
        int n = base + u;
        const float4* xr = (const float4*)(x + (size_t)n * 16);
        float4 xa = xr[0], xb = xr[1], xc = xr[2], xd = xr[3];
        float a0 = sb1[lane], a1 = sb1[lane + 64];
        float xs[16] = {xa.x, xa.y, xa.z, xa.w, xb.x, xb.y, xb.z, xb.w,
                        xc.x, xc.y, xc.z, xc.w, xd.x, xd.y, xd.z, xd.w};
        #pragma unroll
        for (int j = 0; j < 16; ++j) {
            a0 = fmaf(xs[j], sW1[j * 128 + lane], a0);
            a1 = fmaf(xs[j], sW1[j * 128 + 64 + lane], a1);
        }
        a0 = fmaxf(a0, 0.f); a1 = fmaxf(a1, 0.f);
        float p0 = fmaf(a0, sv[lane],       a1 * sv[lane + 64]);
        float p1 = fmaf(a0, sv[128 + lane], a1 * sv[128 + lane + 64]);
        float p2 = fmaf(a0, sv[256 + lane], a1 * sv[256 + lane + 64]);
        #pragma unroll
        for (int s = 32; s; s >>= 1) {
            p0 += __shfl_xor(p0, s);
            p1 += __shfl_xor(p1, s);
            p2 += __shfl_xor(p2, s);
        }
        if (lane == 0)
            d4[n] = make_float4(p0 + sc[0], p1 + sc[1], p2 + sc[2], 0.f);
    }
}

// one block per graph: 3x (key gen + bitonic sort + select) + final GEMV
__global__ __launch_bounds__(256) void k2_cascade(
    const float* __restrict__ x,
    const float* __restrict__ W1,
    const float* __restrict__ b1,
    const float* __restrict__ W2,
    const float* __restrict__ b2,
    const float4* __restrict__ d4,
    float* __restrict__ out)        // [32][128]
{
    __shared__ float d0[NPG], d1[NPG], d2[NPG];
    __shared__ float csc[NPG];
    __shared__ int alive[NPG];
    __shared__ unsigned long long key[NPG];
    __shared__ int sel[256];
    __shared__ float sW1[2048];
    __shared__ float sb1[128];
    __shared__ float Spart[256];
    __shared__ float Svec[128];
    __shared__ float red4[4];
    int t = threadIdx.x;
    int g = blockIdx.x;

    for (int n = t; n < NPG; n += 256) {
        float4 dd = d4[g * NPG + n];
        d0[n] = dd.x; d1[n] = dd.y; d2[n] = dd.z;
        csc[n] = 1.f; alive[n] = 1;
    }
    for (int i = t; i < 2048; i += 256) sW1[i] = W1[i];
    if (t < 128) sb1[t] = b1[t];
    __syncthreads();

    for (int r = 0; r < 3; ++r) {
        int kk = 1024 >> r;
        const float* dr = (r == 0) ? d0 : (r == 1) ? d1 : d2;
        // composite key: (monotonic float bits << 32) | ~idx
        // -> sort desc == (value desc, idx asc), exactly lax.top_k semantics
        for (int n = t; n < NPG; n += 256) {
            unsigned long long kv = 0ull;   // dead nodes sort last
            if (alive[n]) {
                float s = tanhf(csc[n] * dr[n]);
                unsigned int bb = __float_as_uint(s);
                unsigned int m = (bb & 0x80000000u) ? ~bb : (bb | 0x80000000u);
                kv = ((unsigned long long)m << 32)
                   | (unsigned int)(~(unsigned int)n);
            }
            key[n] = kv;
        }
        // bitonic sort, descending, 2048 u64 keys
        for (int k = 2; k <= NPG; k <<= 1) {
            for (int j = k >> 1; j > 0; j >>= 1) {
                __syncthreads();
                for (int i = t; i < NPG; i += 256) {
                    int ixj = i ^ j;
                    if (ixj > i) {
                        unsigned long long a = key[i], b = key[ixj];
                        bool sw = ((i & k) == 0) ? (a < b) : (a > b);
                        if (sw) { key[i] = b; key[ixj] = a; }
                    }
                }
            }
        }
        __syncthreads();
        for (int n = t; n < NPG; n += 256) alive[n] = 0;
        __syncthreads();
        for (int i = t; i < kk; i += 256) {
            unsigned long long kv = key[i];
            int n = (int)(~(unsigned int)kv);
            unsigned int m = (unsigned int)(kv >> 32);
            unsigned int bb = (m & 0x80000000u) ? (m & 0x7FFFFFFFu) : ~m;
            float s = __uint_as_float(bb);  // exact tanh value, decoded back
            alive[n] = 1;
            csc[n] *= s;
            if (r == 2) sel[i] = n;
        }
        __syncthreads();
    }

    // S[f] = sum_{sel} c_n * relu(x_n @ W1 + b1)[f]   (two 128-thread halves)
    {
        int f = t & 127, half = t >> 7;
        float Sacc = 0.f;
        for (int it = half; it < 256; it += 2) {
            int n = sel[it];
            float cn = csc[n];
            const float4* xr = (const float4*)(x + (size_t)(g * NPG + n) * 16);
            float4 xa = xr[0], xb = xr[1], xc = xr[2], xd = xr[3];
            float acc = sb1[f];
            acc = fmaf(xa.x, sW1[0 * 128 + f], acc);
            acc = fmaf(xa.y, sW1[1 * 128 + f], acc);
            acc = fmaf(xa.z, sW1[2 * 128 + f], acc);
            acc = fmaf(xa.w, sW1[3 * 128 + f], acc);
            acc = fmaf(xb.x, sW1[4 * 128 + f], acc);
            acc = fmaf(xb.y, sW1[5 * 128 + f], acc);
            acc = fmaf(xb.z, sW1[6 * 128 + f], acc);
            acc = fmaf(xb.w, sW1[7 * 128 + f], acc);
            acc = fmaf(xc.x, sW1[8 * 128 + f], acc);
            acc = fmaf(xc.y, sW1[9 * 128 + f], acc);
            acc = fmaf(xc.z, sW1[10 * 128 + f], acc);
            acc = fmaf(xc.w, sW1[11 * 128 + f], acc);
            acc = fmaf(xd.x, sW1[12 * 128 + f], acc);
            acc = fmaf(xd.y, sW1[13 * 128 + f], acc);
            acc = fmaf(xd.z, sW1[14 * 128 + f], acc);
            acc = fmaf(xd.w, sW1[15 * 128 + f], acc);
            Sacc += fmaxf(acc, 0.f) * cn;
        }
        Spart[t] = Sacc;
    }
    // Csum = sum_{sel} c_n  (256 threads, one sel each)
    float cpart = csc[sel[t]];
    #pragma unroll
    for (int s = 32; s; s >>= 1) cpart += __shfl_xor(cpart, s);
    if ((t & 63) == 0) red4[t >> 6] = cpart;
    __syncthreads();
    if (t < 128) Svec[t] = Spart[t] + Spart[t + 128];
    __syncthreads();
    if (t < 128) {
        float Csum = red4[0] + red4[1] + red4[2] + red4[3];
        float acc = Csum * b2[t];
        for (int j = 0; j < 128; ++j)
            acc = fmaf(Svec[j], W2[j * 128 + t], acc);
        out[g * 128 + t] = acc * (1.0f / 256.0f);
    }
}

extern "C" void kernel_launch(void* const* d_in, const int* in_sizes, int n_in,
                              void* d_out, int out_size, void* d_ws, size_t ws_size,
                              hipStream_t stream) {
    const float* x  = (const float*)d_in[0];
    const float* W1 = (const float*)d_in[2];   // node_w1 [16][128]
    const float* b1 = (const float*)d_in[3];   // node_b1 [128]
    const float* W2 = (const float*)d_in[4];   // node_w2 [128][128]
    const float* b2 = (const float*)d_in[5];   // node_b2 [128]
    const float* pw = (const float*)d_in[22];  // pool_w  [3][128]
    float* out = (float*)d_out;

    float* wsf = (float*)d_ws;
    float* vws = wsf;              // [3][128]
    float* cws = wsf + 384;        // [4]
    float4* d4 = (float4*)(wsf + 1024);  // [65536] float4 = 1 MB

    k0_prep<<<1, 256, 0, stream>>>(pw, W2, b2, vws, cws);
    k1_dots<<<1024, 256, 0, stream>>>(x, W1, b1, vws, cws, d4);
    k2_cascade<<<NGRAPH, 256, 0, stream>>>(x, W1, b1, W2, b2, d4, out);
}

// Round 2
// 269.914 us; speedup vs baseline: 1.6432x; 1.6432x over previous
//
#include <hip/hip_runtime.h>
#include <hip/hip_bf16.h>

// GraphEncoder: the entire edge/message/update pipeline in the reference is
// dead code (update() output is discarded; h is only ever scaled per-node by
// pooling scores). Live computation:
//   a_n = relu(x_n @ W1 + b1)                       (128-dim, per node)
//   d_{n,k} = a_n . (W2 @ w_k/||w_k||) + b2.(w_k/||w_k||)   k=0..2
//   cascade: s = tanh(c * d_k) on alive nodes, top-k per graph (1024/512/256),
//            c *= s on survivors
//   out_g = ((sum_sel c_n a_n) @ W2 + (sum c_n) b2) / 256
//
// R2: top-k via 8-pass radix-select on u64 key (monotone tanh bits | ~idx)
// instead of full bitonic sort: same selected set bit-for-bit, ~8x less
// barrier-separated LDS work in the latency-bound 1-block-per-graph kernel.

#define NPG    2048
#define NGRAPH 32

__global__ __launch_bounds__(256) void k0_prep(
    const float* __restrict__ pw,   // pool_w [3][128]
    const float* __restrict__ W2,   // [128][128]
    const float* __restrict__ b2,   // [128]
    float* __restrict__ vout,       // [3][128]
    float* __restrict__ cout)       // [4]
{
    __shared__ float swn[384];
    __shared__ float snorm[3];
    int t = threadIdx.x;
    int lane = t & 63, wv = t >> 6;
    if (wv < 3) {
        float w0 = pw[wv * 128 + lane];
        float w1 = pw[wv * 128 + 64 + lane];
        float p = w0 * w0 + w1 * w1;
        #pragma unroll
        for (int s = 32; s; s >>= 1) p += __shfl_xor(p, s);
        if (lane == 0) snorm[wv] = sqrtf(p);
    }
    __syncthreads();
    for (int i = t; i < 384; i += 256) swn[i] = pw[i] / snorm[i >> 7];
    __syncthreads();
    // 3*129 dot-products of length 128 (j==128 row is b2 -> c_k)
    for (int task = wv; task < 3 * 129; task += 4) {
        int k = task / 129, j = task % 129;
        const float* row = (j < 128) ? (W2 + j * 128) : b2;
        float p = row[lane] * swn[k * 128 + lane]
                + row[lane + 64] * swn[k * 128 + lane + 64];
        #pragma unroll
        for (int s = 32; s; s >>= 1) p += __shfl_xor(p, s);
        if (lane == 0) {
            if (j < 128) vout[k * 128 + j] = p;
            else cout[k] = p;
        }
    }
}

__global__ __launch_bounds__(256) void k1_dots(
    const float* __restrict__ x,    // [65536][16]
    const float* __restrict__ W1,   // [16][128]
    const float* __restrict__ b1,   // [128]
    const float* __restrict__ vws,  // [3][128]
    const float* __restrict__ cws,  // [4]
    float4* __restrict__ d4)        // [65536] {d0,d1,d2,_}
{
    __shared__ float sW1[2048];
    __shared__ float sb1[128];
    __shared__ float sv[384];
    __shared__ float sc[4];
    int t = threadIdx.x;
    for (int i = t; i < 2048; i += 256) sW1[i] = W1[i];
    if (t < 128) sb1[t] = b1[t];
    for (int i = t; i < 384; i += 256) sv[i] = vws[i];
    if (t < 4) sc[t] = cws[t];
    __syncthreads();
    int lane = t & 63, wv = t >> 6;
    int base = blockIdx.x * 64 + wv * 16;   // wave processes 16 nodes
    for (int u = 0; u < 16; ++u) {
        int n = base + u;
        const float4* xr = (const float4*)(x + (size_t)n * 16);
        float4 xa = xr[0], xb = xr[1], xc = xr[2], xd = xr[3];
        float a0 = sb1[lane], a1 = sb1[lane + 64];
        float xs[16] = {xa.x, xa.y, xa.z, xa.w, xb.x, xb.y, xb.z, xb.w,
                        xc.x, xc.y, xc.z, xc.w, xd.x, xd.y, xd.z, xd.w};
        #pragma unroll
        for (int j = 0; j < 16; ++j) {
            a0 = fmaf(xs[j], sW1[j * 128 + lane], a0);
            a1 = fmaf(xs[j], sW1[j * 128 + 64 + lane], a1);
        }
        a0 = fmaxf(a0, 0.f); a1 = fmaxf(a1, 0.f);
        float p0 = fmaf(a0, sv[lane],       a1 * sv[lane + 64]);
        float p1 = fmaf(a0, sv[128 + lane], a1 * sv[128 + lane + 64]);
        float p2 = fmaf(a0, sv[256 + lane], a1 * sv[256 + lane + 64]);
        #pragma unroll
        for (int s = 32; s; s >>= 1) {
            p0 += __shfl_xor(p0, s);
            p1 += __shfl_xor(p1, s);
            p2 += __shfl_xor(p2, s);
        }
        if (lane == 0)
            d4[n] = make_float4(p0 + sc[0], p1 + sc[1], p2 + sc[2], 0.f);
    }
}

// one block per graph: 3x (key gen + radix select) + final GEMV
__global__ __launch_bounds__(256) void k2_cascade(
    const float* __restrict__ x,
    const float* __restrict__ W1,
    const float* __restrict__ b1,
    const float* __restrict__ W2,
    const float* __restrict__ b2,
    const float4* __restrict__ d4,
    float* __restrict__ out)        // [32][128]
{
    __shared__ float d0[NPG], d1[NPG], d2[NPG];
    __shared__ float csc[NPG];
    __shared__ int alive[NPG];
    __shared__ unsigned long long key[NPG];
    __shared__ int sel[256];
    __shared__ float sW1[2048];
    __shared__ float sb1[128];
    __shared__ float Spart[256];
    __shared__ float Svec[128];
    __shared__ float red4[4];
    __shared__ unsigned int hist[256];
    __shared__ unsigned long long sPrefix;
    __shared__ int sNeed;
    __shared__ int sCount;
    int t = threadIdx.x;
    int g = blockIdx.x;

    for (int n = t; n < NPG; n += 256) {
        float4 dd = d4[g * NPG + n];
        d0[n] = dd.x; d1[n] = dd.y; d2[n] = dd.z;
        csc[n] = 1.f; alive[n] = 1;
    }
    for (int i = t; i < 2048; i += 256) sW1[i] = W1[i];
    if (t < 128) sb1[t] = b1[t];
    __syncthreads();

    for (int r = 0; r < 3; ++r) {
        int kk = 1024 >> r;
        const float* dr = (r == 0) ? d0 : (r == 1) ? d1 : d2;
        // composite key: (monotonic float bits << 32) | ~idx
        // -> order desc == (value desc, idx asc), exactly lax.top_k semantics
        for (int n = t; n < NPG; n += 256) {
            unsigned long long kv = 0ull;   // dead nodes sort last
            if (alive[n]) {
                float s = tanhf(csc[n] * dr[n]);
                unsigned int bb = __float_as_uint(s);
                unsigned int m = (bb & 0x80000000u) ? ~bb : (bb | 0x80000000u);
                kv = ((unsigned long long)m << 32)
                   | (unsigned int)(~(unsigned int)n);
            }
            key[n] = kv;
        }
        if (t == 0) { sPrefix = 0ull; sNeed = kk; sCount = 0; }
        __syncthreads();

        // 8-pass radix select (8-bit digits, MSB first) for kk-th largest key
        for (int pass = 0; pass < 8; ++pass) {
            int shift = 56 - 8 * pass;
            hist[t] = 0u;
            __syncthreads();
            unsigned long long pref = sPrefix;
            unsigned int need = (unsigned int)sNeed;
            for (int n = t; n < NPG; n += 256) {
                unsigned long long kv = key[n];
                bool cand = (pass == 0) ||
                            (((kv ^ pref) >> (shift + 8)) == 0ull);
                if (cand)
                    atomicAdd(&hist[(unsigned int)(kv >> shift) & 255u], 1u);
            }
            __syncthreads();
            if (t < 64) {   // wave 0: find boundary bucket, no barriers inside
                int L = t;
                unsigned int h0 = hist[4 * L + 0];
                unsigned int h1 = hist[4 * L + 1];
                unsigned int h2 = hist[4 * L + 2];
                unsigned int h3 = hist[4 * L + 3];
                unsigned int tl = h0 + h1 + h2 + h3;
                unsigned int s = tl;            // inclusive suffix-sum over lanes
                #pragma unroll
                for (int dlt = 1; dlt < 64; dlt <<= 1) {
                    unsigned int v = __shfl_down(s, dlt);
                    if (L + dlt < 64) s += v;
                }
                unsigned int above = s - tl;    // sum over lanes > L
                unsigned int c3 = above + h3;
                unsigned int c2 = c3 + h2;
                unsigned int c1 = c2 + h1;
                unsigned int c0 = c1 + h0;      // cum(b) = #cands in buckets >= b
                int bl = -1;
                if (c3 >= need) bl = 4 * L + 3;
                else if (c2 >= need) bl = 4 * L + 2;
                else if (c1 >= need) bl = 4 * L + 1;
                else if (c0 >= need) bl = 4 * L + 0;
                int bstar = bl;
                #pragma unroll
                for (int dlt = 1; dlt < 64; dlt <<= 1)
                    bstar = max(bstar, __shfl_xor(bstar, dlt));
                if (bl == bstar && bstar >= 0) {   // owner lane updates state
                    unsigned int cb, hb;
                    int o = bstar & 3;
                    cb = (o == 0) ? c0 : (o == 1) ? c1 : (o == 2) ? c2 : c3;
                    hb = (o == 0) ? h0 : (o == 1) ? h1 : (o == 2) ? h2 : h3;
                    sNeed = (int)(need - (cb - hb));
                    sPrefix = pref | ((unsigned long long)(unsigned int)bstar << shift);
                }
            }
            __syncthreads();
        }
        unsigned long long thr = sPrefix;   // exact kk-th largest key
        for (int n = t; n < NPG; n += 256) alive[n] = 0;
        __syncthreads();
        // select: keys are distinct -> exactly kk nodes have key >= thr
        for (int n = t; n < NPG; n += 256) {
            unsigned long long kv = key[n];
            if (kv >= thr) {
                unsigned int m = (unsigned int)(kv >> 32);
                unsigned int bb = (m & 0x80000000u) ? (m & 0x7FFFFFFFu) : ~m;
                float s = __uint_as_float(bb);  // exact tanh value decoded back
                alive[n] = 1;
                csc[n] *= s;
                if (r == 2) sel[atomicAdd(&sCount, 1)] = n;
            }
        }
        __syncthreads();
    }

    // S[f] = sum_{sel} c_n * relu(x_n @ W1 + b1)[f]   (two 128-thread halves)
    {
        int f = t & 127, half = t >> 7;
        float Sacc = 0.f;
        for (int it = half; it < 256; it += 2) {
            int n = sel[it];
            float cn = csc[n];
            const float4* xr = (const float4*)(x + (size_t)(g * NPG + n) * 16);
            float4 xa = xr[0], xb = xr[1], xc = xr[2], xd = xr[3];
            float acc = sb1[f];
            acc = fmaf(xa.x, sW1[0 * 128 + f], acc);
            acc = fmaf(xa.y, sW1[1 * 128 + f], acc);
            acc = fmaf(xa.z, sW1[2 * 128 + f], acc);
            acc = fmaf(xa.w, sW1[3 * 128 + f], acc);
            acc = fmaf(xb.x, sW1[4 * 128 + f], acc);
            acc = fmaf(xb.y, sW1[5 * 128 + f], acc);
            acc = fmaf(xb.z, sW1[6 * 128 + f], acc);
            acc = fmaf(xb.w, sW1[7 * 128 + f], acc);
            acc = fmaf(xc.x, sW1[8 * 128 + f], acc);
            acc = fmaf(xc.y, sW1[9 * 128 + f], acc);
            acc = fmaf(xc.z, sW1[10 * 128 + f], acc);
            acc = fmaf(xc.w, sW1[11 * 128 + f], acc);
            acc = fmaf(xd.x, sW1[12 * 128 + f], acc);
            acc = fmaf(xd.y, sW1[13 * 128 + f], acc);
            acc = fmaf(xd.z, sW1[14 * 128 + f], acc);
            acc = fmaf(xd.w, sW1[15 * 128 + f], acc);
            Sacc += fmaxf(acc, 0.f) * cn;
        }
        Spart[t] = Sacc;
    }
    // Csum = sum_{sel} c_n  (256 threads, one sel each)
    float cpart = csc[sel[t]];
    #pragma unroll
    for (int s = 32; s; s >>= 1) cpart += __shfl_xor(cpart, s);
    if ((t & 63) == 0) red4[t >> 6] = cpart;
    __syncthreads();
    if (t < 128) Svec[t] = Spart[t] + Spart[t + 128];
    __syncthreads();
    if (t < 128) {
        float Csum = red4[0] + red4[1] + red4[2] + red4[3];
        float acc = Csum * b2[t];
        for (int j = 0; j < 128; ++j)
            acc = fmaf(Svec[j], W2[j * 128 + t], acc);
        out[g * 128 + t] = acc * (1.0f / 256.0f);
    }
}

extern "C" void kernel_launch(void* const* d_in, const int* in_sizes, int n_in,
                              void* d_out, int out_size, void* d_ws, size_t ws_size,
                              hipStream_t stream) {
    const float* x  = (const float*)d_in[0];
    const float* W1 = (const float*)d_in[2];   // node_w1 [16][128]
    const float* b1 = (const float*)d_in[3];   // node_b1 [128]
    const float* W2 = (const float*)d_in[4];   // node_w2 [128][128]
    const float* b2 = (const float*)d_in[5];   // node_b2 [128]
    const float* pw = (const float*)d_in[22];  // pool_w  [3][128]
    float* out = (float*)d_out;

    float* wsf = (float*)d_ws;
    float* vws = wsf;              // [3][128]
    float* cws = wsf + 384;        // [4]
    float4* d4 = (float4*)(wsf + 1024);  // [65536] float4 = 1 MB

    k0_prep<<<1, 256, 0, stream>>>(pw, W2, b2, vws, cws);
    k1_dots<<<1024, 256, 0, stream>>>(x, W1, b1, vws, cws, d4);
    k2_cascade<<<NGRAPH, 256, 0, stream>>>(x, W1, b1, W2, b2, d4, out);
}

// Round 3
// 177.612 us; speedup vs baseline: 2.4972x; 1.5197x over previous
//
#include <hip/hip_runtime.h>
#include <hip/hip_bf16.h>

// GraphEncoder: the entire edge/message/update pipeline in the reference is
// dead code (update() output is discarded; h is only ever scaled per-node by
// pooling scores). Live computation:
//   a_n = relu(x_n @ W1 + b1)                       (128-dim, per node)
//   d_{n,k} = a_n . (W2 @ w_k/||w_k||) + b2.(w_k/||w_k||)   k=0..2
//   cascade: s = tanh(c * d_k) on alive nodes, top-k per graph (1024/512/256),
//            c *= s on survivors
//   out_g = ((sum_sel c_n a_n) @ W2 + (sum c_n) b2) / 256
//
// R3: (a) k1 restructured thread-per-node (no shuffle chains), k0 folded in;
//     (b) k2 keys on z=c*d (tanh is monotone -> identical selection),
//         43-bit key, 4 passes x 11-bit digits, 1024 threads, padded hist.

#define NPG    2048
#define NGRAPH 32
#define HPAD(b) ((b) + ((b) >> 5))   // 2048 bins -> 2112 padded slots

__global__ __launch_bounds__(256) void k1_fused(
    const float* __restrict__ x,    // [65536][16]
    const float* __restrict__ W1,   // [16][128]
    const float* __restrict__ b1,   // [128]
    const float* __restrict__ W2,   // [128][128]
    const float* __restrict__ b2,   // [128]
    const float* __restrict__ pw,   // pool_w [3][128]
    float4* __restrict__ d4)        // [65536] {d0,d1,d2,_}
{
    __shared__ float4 sW1v[512];                 // W1 as [16][32] float4
    __shared__ float4 sb1v[32];                  // b1
    __shared__ __align__(16) float swn[384];     // normalized pool_w
    __shared__ __align__(16) float sv[384];      // v_k[j] = W2 @ wn_k
    __shared__ float sc[4];                      // c_k = b2 . wn_k
    __shared__ float snorm[3];
    int t = threadIdx.x;
    int lane = t & 63, wv = t >> 6;

    for (int i = t; i < 512; i += 256) sW1v[i] = ((const float4*)W1)[i];
    if (t < 32) sb1v[t] = ((const float4*)b1)[t];
    if (wv < 3) {
        float w0 = pw[wv * 128 + lane];
        float w1 = pw[wv * 128 + 64 + lane];
        float p = w0 * w0 + w1 * w1;
        #pragma unroll
        for (int s = 32; s; s >>= 1) p += __shfl_xor(p, s);
        if (lane == 0) snorm[wv] = sqrtf(p);
    }
    __syncthreads();
    for (int i = t; i < 384; i += 256) swn[i] = pw[i] / snorm[i >> 7];
    __syncthreads();
    // 387 tasks: (k,j) dots of length 128; j==128 -> c_k = b2 . wn_k
    for (int task = t; task < 387; task += 256) {
        int k = task / 129, j = task % 129;
        const float4* r4 = (const float4*)((j < 128) ? (W2 + j * 128) : b2);
        const float* wn = swn + k * 128;
        float p0 = 0.f, p1 = 0.f, p2 = 0.f, p3 = 0.f;
        #pragma unroll 8
        for (int q = 0; q < 32; ++q) {
            float4 w = r4[q];
            p0 = fmaf(w.x, wn[4 * q + 0], p0);
            p1 = fmaf(w.y, wn[4 * q + 1], p1);
            p2 = fmaf(w.z, wn[4 * q + 2], p2);
            p3 = fmaf(w.w, wn[4 * q + 3], p3);
        }
        float p = (p0 + p1) + (p2 + p3);
        if (j < 128) sv[k * 128 + j] = p;
        else sc[k] = p;
    }
    __syncthreads();

    // one node per thread, everything broadcast from LDS
    int n = blockIdx.x * 256 + t;
    const float4* xr = (const float4*)(x + (size_t)n * 16);
    float4 xa = xr[0], xb = xr[1], xc = xr[2], xd = xr[3];
    float xs[16] = {xa.x, xa.y, xa.z, xa.w, xb.x, xb.y, xb.z, xb.w,
                    xc.x, xc.y, xc.z, xc.w, xd.x, xd.y, xd.z, xd.w};
    const float4* sv4 = (const float4*)sv;
    float dd0 = sc[0], dd1 = sc[1], dd2 = sc[2];
    #pragma unroll 4
    for (int fq = 0; fq < 32; ++fq) {
        float4 a4 = sb1v[fq];
        #pragma unroll
        for (int j = 0; j < 16; ++j) {
            float4 w = sW1v[j * 32 + fq];
            a4.x = fmaf(xs[j], w.x, a4.x);
            a4.y = fmaf(xs[j], w.y, a4.y);
            a4.z = fmaf(xs[j], w.z, a4.z);
            a4.w = fmaf(xs[j], w.w, a4.w);
        }
        a4.x = fmaxf(a4.x, 0.f); a4.y = fmaxf(a4.y, 0.f);
        a4.z = fmaxf(a4.z, 0.f); a4.w = fmaxf(a4.w, 0.f);
        float4 v0 = sv4[fq], v1 = sv4[32 + fq], v2 = sv4[64 + fq];
        dd0 = fmaf(a4.x, v0.x, fmaf(a4.y, v0.y, fmaf(a4.z, v0.z, fmaf(a4.w, v0.w, dd0))));
        dd1 = fmaf(a4.x, v1.x, fmaf(a4.y, v1.y, fmaf(a4.z, v1.z, fmaf(a4.w, v1.w, dd1))));
        dd2 = fmaf(a4.x, v2.x, fmaf(a4.y, v2.y, fmaf(a4.z, v2.z, fmaf(a4.w, v2.w, dd2))));
    }
    d4[n] = make_float4(dd0, dd1, dd2, 0.f);
}

// one block per graph: 3x (key gen + 4-pass radix select) + final GEMV
__global__ __launch_bounds__(1024, 1) void k2_cascade(
    const float* __restrict__ x,
    const float* __restrict__ W1,
    const float* __restrict__ b1,
    const float* __restrict__ W2,
    const float* __restrict__ b2,
    const float4* __restrict__ d4,
    float* __restrict__ out)        // [32][128]
{
    __shared__ float d0[NPG], d1[NPG], d2[NPG];
    __shared__ float csc[NPG];
    __shared__ int alive[NPG];
    __shared__ unsigned long long key[NPG];
    __shared__ unsigned int hist[HPAD(2047) + 1];
    __shared__ int sel[256];
    __shared__ float sW1[2048];
    __shared__ float sb1[128];
    __shared__ float Spart[1024];
    __shared__ float Svec[128];
    __shared__ float red4[4];
    __shared__ unsigned long long sPrefix;
    __shared__ int sNeed;
    __shared__ int sCount;
    int t = threadIdx.x;
    int g = blockIdx.x;

    for (int n = t; n < NPG; n += 1024) {
        float4 dd = d4[g * NPG + n];
        d0[n] = dd.x; d1[n] = dd.y; d2[n] = dd.z;
        csc[n] = 1.f; alive[n] = 1;
    }
    for (int i = t; i < 2048; i += 1024) sW1[i] = W1[i];
    if (t < 128) sb1[t] = b1[t];
    if (t == 0) sCount = 0;
    __syncthreads();

    for (int r = 0; r < 3; ++r) {
        int kk = 1024 >> r;
        const float* dr = (r == 0) ? d0 : (r == 1) ? d1 : d2;
        // key on z = c*d (tanh monotone -> same order), 43 bits:
        //   (monotone z bits << 11) | (2047-n)  -> desc == (score desc, idx asc)
        for (int n = t; n < NPG; n += 1024) {
            unsigned long long kv = 0ull;   // dead nodes sort last
            if (alive[n]) {
                float z = csc[n] * dr[n];
                unsigned int bb = __float_as_uint(z);
                unsigned int m = (bb & 0x80000000u) ? ~bb : (bb | 0x80000000u);
                kv = ((unsigned long long)m << 11)
                   | (unsigned long long)(unsigned int)(2047 - n);
            }
            key[n] = kv;
        }
        if (t == 0) { sPrefix = 0ull; sNeed = kk; }
        __syncthreads();

        // 4-pass radix select, 11-bit digits MSB-first, for kk-th largest key
        for (int pass = 0; pass < 4; ++pass) {
            int shift = 33 - 11 * pass;
            for (int i = t; i < HPAD(2047) + 1; i += 1024) hist[i] = 0u;
            __syncthreads();
            unsigned long long pref = sPrefix;
            unsigned int need = (unsigned int)sNeed;
            for (int n = t; n < NPG; n += 1024) {
                unsigned long long kv = key[n];
                bool cand = (pass == 0) ||
                            ((kv >> (shift + 11)) == (pref >> (shift + 11)));
                if (cand) {
                    unsigned int dgt = (unsigned int)(kv >> shift) & 2047u;
                    atomicAdd(&hist[HPAD(dgt)], 1u);
                }
            }
            __syncthreads();
            if (t < 64) {   // wave 0: lane L owns bins [32L, 32L+32)
                unsigned int h[32];
                unsigned int tl = 0;
                #pragma unroll
                for (int b = 0; b < 32; ++b) {
                    h[b] = hist[HPAD(32 * t + b)];
                    tl += h[b];
                }
                unsigned int s = tl;   // inclusive suffix-sum across lanes
                #pragma unroll
                for (int dlt = 1; dlt < 64; dlt <<= 1) {
                    unsigned int v = __shfl_down(s, dlt);
                    if (t + dlt < 64) s += v;
                }
                unsigned int above = s - tl;   // sum over lanes > L
                if (above < need && above + tl >= need) {  // unique owner lane
                    unsigned int cum = above;
                    #pragma unroll
                    for (int b = 31; b >= 0; --b) {
                        cum += h[b];
                        if (cum >= need) {
                            sNeed = (int)(need - (cum - h[b]));
                            sPrefix = pref |
                                ((unsigned long long)(unsigned int)(32 * t + b) << shift);
                            break;
                        }
                    }
                }
            }
            __syncthreads();
        }
        unsigned long long thr = sPrefix;   // exact kk-th largest key
        for (int n = t; n < NPG; n += 1024) alive[n] = 0;
        __syncthreads();
        // keys distinct -> exactly kk nodes have key >= thr
        for (int n = t; n < NPG; n += 1024) {
            if (key[n] >= thr) {
                float s = tanhf(csc[n] * dr[n]);   // tanh only for survivors
                alive[n] = 1;
                csc[n] *= s;
                if (r == 2) sel[atomicAdd(&sCount, 1)] = n;
            }
        }
        __syncthreads();
    }

    // S[f] = sum_{sel} c_n * relu(x_n @ W1 + b1)[f]   (8 x 128-thread halves)
    {
        int f = t & 127, half = t >> 7;
        float Sacc = 0.f;
        for (int it = half; it < 256; it += 8) {
            int n = sel[it];
            float cn = csc[n];
            const float4* xr = (const float4*)(x + (size_t)(g * NPG + n) * 16);
            float4 xa = xr[0], xb = xr[1], xc = xr[2], xd = xr[3];
            float acc = sb1[f];
            acc = fmaf(xa.x, sW1[0 * 128 + f], acc);
            acc = fmaf(xa.y, sW1[1 * 128 + f], acc);
            acc = fmaf(xa.z, sW1[2 * 128 + f], acc);
            acc = fmaf(xa.w, sW1[3 * 128 + f], acc);
            acc = fmaf(xb.x, sW1[4 * 128 + f], acc);
            acc = fmaf(xb.y, sW1[5 * 128 + f], acc);
            acc = fmaf(xb.z, sW1[6 * 128 + f], acc);
            acc = fmaf(xb.w, sW1[7 * 128 + f], acc);
            acc = fmaf(xc.x, sW1[8 * 128 + f], acc);
            acc = fmaf(xc.y, sW1[9 * 128 + f], acc);
            acc = fmaf(xc.z, sW1[10 * 128 + f], acc);
            acc = fmaf(xc.w, sW1[11 * 128 + f], acc);
            acc = fmaf(xd.x, sW1[12 * 128 + f], acc);
            acc = fmaf(xd.y, sW1[13 * 128 + f], acc);
            acc = fmaf(xd.z, sW1[14 * 128 + f], acc);
            acc = fmaf(xd.w, sW1[15 * 128 + f], acc);
            Sacc += fmaxf(acc, 0.f) * cn;
        }
        Spart[t] = Sacc;
    }
    if (t < 256) {   // Csum = sum_{sel} c_n
        float cpart = csc[sel[t]];
        #pragma unroll
        for (int s = 32; s; s >>= 1) cpart += __shfl_xor(cpart, s);
        if ((t & 63) == 0) red4[t >> 6] = cpart;
    }
    __syncthreads();
    if (t < 128) {
        float sv = 0.f;
        #pragma unroll
        for (int h = 0; h < 8; ++h) sv += Spart[h * 128 + t];
        Svec[t] = sv;
    }
    __syncthreads();
    if (t < 128) {
        float Csum = (red4[0] + red4[1]) + (red4[2] + red4[3]);
        float acc = Csum * b2[t];
        for (int j = 0; j < 128; ++j)
            acc = fmaf(Svec[j], W2[j * 128 + t], acc);
        out[g * 128 + t] = acc * (1.0f / 256.0f);
    }
}

extern "C" void kernel_launch(void* const* d_in, const int* in_sizes, int n_in,
                              void* d_out, int out_size, void* d_ws, size_t ws_size,
                              hipStream_t stream) {
    const float* x  = (const float*)d_in[0];
    const float* W1 = (const float*)d_in[2];   // node_w1 [16][128]
    const float* b1 = (const float*)d_in[3];   // node_b1 [128]
    const float* W2 = (const float*)d_in[4];   // node_w2 [128][128]
    const float* b2 = (const float*)d_in[5];   // node_b2 [128]
    const float* pw = (const float*)d_in[22];  // pool_w  [3][128]
    float* out = (float*)d_out;

    float4* d4 = (float4*)d_ws;   // [65536] float4 = 1 MB

    k1_fused<<<256, 256, 0, stream>>>(x, W1, b1, W2, b2, pw, d4);
    k2_cascade<<<NGRAPH, 1024, 0, stream>>>(x, W1, b1, W2, b2, d4, out);
}

// Round 5
// 168.176 us; speedup vs baseline: 2.6373x; 1.0561x over previous
//
#include <hip/hip_runtime.h>
#include <hip/hip_bf16.h>

// GraphEncoder: the entire edge/message/update pipeline in the reference is
// dead code (update() output is discarded; h is only ever scaled per-node by
// pooling scores). Live computation:
//   a_n = relu(x_n @ W1 + b1)                       (128-dim, per node)
//   d_{n,k} = a_n . (W2 @ w_k/||w_k||) + b2.(w_k/||w_k||)   k=0..2
//   cascade: s = tanh(c * d_k) on alive nodes, top-k per graph (1024/512/256),
//            c *= s on survivors
//   out_g = ((sum_sel c_n a_n) @ W2 + (sum c_n) b2) / 256
//
// R4 (resubmit; R4 bench was lost to GPU-acquisition timeout):
// k2 restructured: survivor compaction (loop extents 2048/1024/512),
// keygen fused with radix pass 0, early-exit radix (boundary-bucket count ==
// remaining need -> threshold resolved; typically ~2 passes/round not 4),
// double-buffered histogram zeroed concurrently with the scan, and
// ballot-aggregated compaction (1 LDS atomic per wave, not per thread).
// Selection is bit-for-bit identical to the sort formulation.

#define NPG    2048
#define NGRAPH 32
#define HP     2112
#define HPAD(b) ((b) + ((b) >> 5))   // pad: bin -> slot, kills bank aliasing

__global__ __launch_bounds__(256) void k1_fused(
    const float* __restrict__ x,    // [65536][16]
    const float* __restrict__ W1,   // [16][128]
    const float* __restrict__ b1,   // [128]
    const float* __restrict__ W2,   // [128][128]
    const float* __restrict__ b2,   // [128]
    const float* __restrict__ pw,   // pool_w [3][128]
    float4* __restrict__ d4)        // [65536] {d0,d1,d2,_}
{
    __shared__ float4 sW1v[512];                 // W1 as [16][32] float4
    __shared__ float4 sb1v[32];                  // b1
    __shared__ __align__(16) float swn[384];     // normalized pool_w
    __shared__ __align__(16) float sv[384];      // v_k[j] = W2 @ wn_k
    __shared__ float sc[4];                      // c_k = b2 . wn_k
    __shared__ float snorm[3];
    int t = threadIdx.x;
    int lane = t & 63, wv = t >> 6;

    for (int i = t; i < 512; i += 256) sW1v[i] = ((const float4*)W1)[i];
    if (t < 32) sb1v[t] = ((const float4*)b1)[t];
    if (wv < 3) {
        float w0 = pw[wv * 128 + lane];
        float w1 = pw[wv * 128 + 64 + lane];
        float p = w0 * w0 + w1 * w1;
        #pragma unroll
        for (int s = 32; s; s >>= 1) p += __shfl_xor(p, s);
        if (lane == 0) snorm[wv] = sqrtf(p);
    }
    __syncthreads();
    for (int i = t; i < 384; i += 256) swn[i] = pw[i] / snorm[i >> 7];
    __syncthreads();
    // 387 tasks: (k,j) dots of length 128; j==128 -> c_k = b2 . wn_k
    for (int task = t; task < 387; task += 256) {
        int k = task / 129, j = task % 129;
        const float4* r4 = (const float4*)((j < 128) ? (W2 + j * 128) : b2);
        const float* wn = swn + k * 128;
        float p0 = 0.f, p1 = 0.f, p2 = 0.f, p3 = 0.f;
        #pragma unroll 8
        for (int q = 0; q < 32; ++q) {
            float4 w = r4[q];
            p0 = fmaf(w.x, wn[4 * q + 0], p0);
            p1 = fmaf(w.y, wn[4 * q + 1], p1);
            p2 = fmaf(w.z, wn[4 * q + 2], p2);
            p3 = fmaf(w.w, wn[4 * q + 3], p3);
        }
        float p = (p0 + p1) + (p2 + p3);
        if (j < 128) sv[k * 128 + j] = p;
        else sc[k] = p;
    }
    __syncthreads();

    // one node per thread, everything broadcast from LDS
    int n = blockIdx.x * 256 + t;
    const float4* xr = (const float4*)(x + (size_t)n * 16);
    float4 xa = xr[0], xb = xr[1], xc = xr[2], xd = xr[3];
    float xs[16] = {xa.x, xa.y, xa.z, xa.w, xb.x, xb.y, xb.z, xb.w,
                    xc.x, xc.y, xc.z, xc.w, xd.x, xd.y, xd.z, xd.w};
    const float4* sv4 = (const float4*)sv;
    float dd0 = sc[0], dd1 = sc[1], dd2 = sc[2];
    #pragma unroll 4
    for (int fq = 0; fq < 32; ++fq) {
        float4 a4 = sb1v[fq];
        #pragma unroll
        for (int j = 0; j < 16; ++j) {
            float4 w = sW1v[j * 32 + fq];
            a4.x = fmaf(xs[j], w.x, a4.x);
            a4.y = fmaf(xs[j], w.y, a4.y);
            a4.z = fmaf(xs[j], w.z, a4.z);
            a4.w = fmaf(xs[j], w.w, a4.w);
        }
        a4.x = fmaxf(a4.x, 0.f); a4.y = fmaxf(a4.y, 0.f);
        a4.z = fmaxf(a4.z, 0.f); a4.w = fmaxf(a4.w, 0.f);
        float4 v0 = sv4[fq], v1 = sv4[32 + fq], v2 = sv4[64 + fq];
        dd0 = fmaf(a4.x, v0.x, fmaf(a4.y, v0.y, fmaf(a4.z, v0.z, fmaf(a4.w, v0.w, dd0))));
        dd1 = fmaf(a4.x, v1.x, fmaf(a4.y, v1.y, fmaf(a4.z, v1.z, fmaf(a4.w, v1.w, dd1))));
        dd2 = fmaf(a4.x, v2.x, fmaf(a4.y, v2.y, fmaf(a4.z, v2.z, fmaf(a4.w, v2.w, dd2))));
    }
    d4[n] = make_float4(dd0, dd1, dd2, 0.f);
}

// one block per graph: 3x (fused keygen/hist0 + early-exit radix + ballot
// compaction) + final gather-GEMV
__global__ __launch_bounds__(1024, 1) void k2_cascade(
    const float* __restrict__ x,
    const float* __restrict__ W1,
    const float* __restrict__ b1,
    const float* __restrict__ W2,
    const float* __restrict__ b2,
    const float4* __restrict__ d4,
    float* __restrict__ out)        // [32][128]
{
    __shared__ float d0A[NPG], d1A[NPG], d2A[NPG];
    __shared__ unsigned long long sKey[NPG];
    __shared__ unsigned int hist[2][HP];
    __shared__ int   idxB[1024];
    __shared__ float cscB[1024], d1B[1024], d2B[1024];
    __shared__ int   idxA2[512];
    __shared__ float cscA2[512], d2A2[512];
    __shared__ float sW1[2048], sb1[128];
    __shared__ float Spart[1024], Svec[128], red4[4];
    __shared__ unsigned long long sPrefix;
    __shared__ int sNeed, sDone, sCnt;

    int t = threadIdx.x, g = blockIdx.x;
    int lane = t & 63, wv = t >> 6;

    for (int n = t; n < NPG; n += 1024) {
        float4 dd = d4[g * NPG + n];
        d0A[n] = dd.x; d1A[n] = dd.y; d2A[n] = dd.z;
    }
    for (int i = t; i < 2048; i += 1024) sW1[i] = W1[i];
    if (t < 128) sb1[t] = b1[t];
    for (int i = t; i < 2 * HP; i += 1024) ((unsigned int*)hist)[i] = 0u;
    __syncthreads();

    int curN = NPG;
    for (int r = 0; r < 3; ++r) {
        int kk = 1024 >> r;
        const float* dIn   = (r == 0) ? d0A : (r == 1) ? d1B : d2A2;
        const float* cscIn = (r == 0) ? (const float*)0 : (r == 1) ? cscB : cscA2;
        const int*   idxIn = (r == 0) ? (const int*)0 : (r == 1) ? idxB : idxA2;
        int*   idxOut = (r == 1) ? idxA2 : idxB;
        float* cscOut = (r == 1) ? cscA2 : cscB;

        if (t == 0) { sPrefix = 0ull; sNeed = kk; sDone = 0; sCnt = 0; }
        // keygen + pass-0 histogram fused (key stays in register for hist0).
        // key = mono(z)<<11 | (2047-n): desc == (score desc, idx asc), the
        // exact lax.top_k order; tanh monotone -> rank by z = c*d directly.
        for (int m = t; m < curN; m += 1024) {
            float ci = cscIn ? cscIn[m] : 1.f;
            int   ni = idxIn ? idxIn[m] : m;
            float z = ci * dIn[m];
            unsigned int bb = __float_as_uint(z);
            unsigned int mo = (bb & 0x80000000u) ? ~bb : (bb | 0x80000000u);
            unsigned long long kv = ((unsigned long long)mo << 11)
                                  | (unsigned long long)(unsigned int)(2047 - ni);
            sKey[m] = kv;
            atomicAdd(&hist[0][HPAD((unsigned int)(kv >> 33) & 2047u)], 1u);
        }
        __syncthreads();

        int lastBuf = 0;
        for (int pass = 0; pass < 4; ++pass) {
            int buf = pass & 1;
            int shift = 33 - 11 * pass;
            lastBuf = buf;
            if (pass > 0) {  // histogram candidates under current prefix
                unsigned long long pref = sPrefix;
                for (int m = t; m < curN; m += 1024) {
                    unsigned long long kv = sKey[m];
                    if ((kv >> (shift + 11)) == (pref >> (shift + 11)))
                        atomicAdd(&hist[buf][HPAD((unsigned int)(kv >> shift) & 2047u)], 1u);
                }
                __syncthreads();
            }
            if (wv == 0) {   // wave 0: scan 2048 bins, lane L owns [32L,32L+32)
                unsigned long long pref = sPrefix;
                unsigned int need = (unsigned int)sNeed;
                unsigned int h[32], tl = 0;
                #pragma unroll
                for (int b = 0; b < 32; ++b) {
                    h[b] = hist[buf][HPAD(32u * t + b)];
                    tl += h[b];
                }
                unsigned int s = tl;   // inclusive suffix-sum across lanes
                #pragma unroll
                for (int d = 1; d < 64; d <<= 1) {
                    unsigned int v = __shfl_down(s, d);
                    if (t + d < 64) s += v;
                }
                unsigned int above = s - tl;   // sum over lanes > L
                if (above < need && above + tl >= need) {   // unique owner
                    unsigned int cum = above;
                    #pragma unroll
                    for (int b = 31; b >= 0; --b) {
                        cum += h[b];
                        if (cum >= need) {
                            int nn = (int)(need - (cum - h[b]));
                            sNeed = nn;
                            sPrefix = pref |
                                ((unsigned long long)(unsigned int)(32 * t + b) << shift);
                            // early exit: whole boundary bucket selected ->
                            // thr = prefix (low bits 0) picks exactly kk keys
                            sDone = (nn == (int)h[b]) || (pass == 3);
                            break;
                        }
                    }
                }
            } else if (pass > 0) {
                // waves 1..15: zero the other buffer (used by previous pass,
                // needed zero by the next one) while wave 0 scans
                for (int i = t - 64; i < HP; i += 960) hist[buf ^ 1][i] = 0u;
            }
            __syncthreads();
            if (sDone) break;
        }
        unsigned long long thr = sPrefix;

        // compaction (ballot-aggregated: one LDS atomic per wave-iteration)
        // + zero the one still-dirty hist buffer for the next round
        for (int i = t; i < HP; i += 1024) hist[lastBuf][i] = 0u;
        for (int m = t; m < curN; m += 1024) {
            unsigned long long kv = sKey[m];
            bool pred = (kv >= thr);   // keys distinct -> exactly kk selected
            unsigned long long mask = __ballot(pred);
            if (mask) {
                int leader = __ffsll((long long)mask) - 1;
                int cnt = __popcll(mask);
                int base = 0;
                if (lane == leader) base = atomicAdd(&sCnt, cnt);
                base = __shfl(base, leader);
                if (pred) {
                    int rank = __popcll(mask & ((1ull << lane) - 1ull));
                    int pos = base + rank;
                    float ci = cscIn ? cscIn[m] : 1.f;
                    int   ni = idxIn ? idxIn[m] : m;
                    float z = ci * dIn[m];
                    idxOut[pos] = ni;
                    cscOut[pos] = ci * tanhf(z);   // tanh only for survivors
                    if (r == 0)      { d1B[pos] = d1A[m]; d2B[pos] = d2A[m]; }
                    else if (r == 1) { d2A2[pos] = d2B[m]; }
                }
            }
        }
        __syncthreads();
        curN = kk;
    }

    // S[f] = sum_{sel} c_n * relu(x_n @ W1 + b1)[f]; sel/csc in idxB/cscB[0..256)
    {
        int f = t & 127, grp = t >> 7;
        float Sacc = 0.f;
        for (int it = grp; it < 256; it += 8) {
            int n = idxB[it];
            float cn = cscB[it];
            const float4* xr = (const float4*)(x + (size_t)(g * NPG + n) * 16);
            float4 xa = xr[0], xb = xr[1], xc = xr[2], xd = xr[3];
            float acc = sb1[f];
            acc = fmaf(xa.x, sW1[0 * 128 + f], acc);
            acc = fmaf(xa.y, sW1[1 * 128 + f], acc);
            acc = fmaf(xa.z, sW1[2 * 128 + f], acc);
            acc = fmaf(xa.w, sW1[3 * 128 + f], acc);
            acc = fmaf(xb.x, sW1[4 * 128 + f], acc);
            acc = fmaf(xb.y, sW1[5 * 128 + f], acc);
            acc = fmaf(xb.z, sW1[6 * 128 + f], acc);
            acc = fmaf(xb.w, sW1[7 * 128 + f], acc);
            acc = fmaf(xc.x, sW1[8 * 128 + f], acc);
            acc = fmaf(xc.y, sW1[9 * 128 + f], acc);
            acc = fmaf(xc.z, sW1[10 * 128 + f], acc);
            acc = fmaf(xc.w, sW1[11 * 128 + f], acc);
            acc = fmaf(xd.x, sW1[12 * 128 + f], acc);
            acc = fmaf(xd.y, sW1[13 * 128 + f], acc);
            acc = fmaf(xd.z, sW1[14 * 128 + f], acc);
            acc = fmaf(xd.w, sW1[15 * 128 + f], acc);
            Sacc += fmaxf(acc, 0.f) * cn;
        }
        Spart[t] = Sacc;
    }
    if (t < 256) {   // Csum = sum_{sel} c_n
        float cpart = cscB[t];
        #pragma unroll
        for (int s = 32; s; s >>= 1) cpart += __shfl_xor(cpart, s);
        if ((t & 63) == 0) red4[t >> 6] = cpart;
    }
    __syncthreads();
    if (t < 128) {
        float sv = 0.f;
        #pragma unroll
        for (int h = 0; h < 8; ++h) sv += Spart[h * 128 + t];
        Svec[t] = sv;
    }
    __syncthreads();
    if (t < 128) {
        float Csum = (red4[0] + red4[1]) + (red4[2] + red4[3]);
        float acc = Csum * b2[t];
        for (int j = 0; j < 128; ++j)
            acc = fmaf(Svec[j], W2[j * 128 + t], acc);
        out[g * 128 + t] = acc * (1.0f / 256.0f);
    }
}

extern "C" void kernel_launch(void* const* d_in, const int* in_sizes, int n_in,
                              void* d_out, int out_size, void* d_ws, size_t ws_size,
                              hipStream_t stream) {
    const float* x  = (const float*)d_in[0];
    const float* W1 = (const float*)d_in[2];   // node_w1 [16][128]
    const float* b1 = (const float*)d_in[3];   // node_b1 [128]
    const float* W2 = (const float*)d_in[4];   // node_w2 [128][128]
    const float* b2 = (const float*)d_in[5];   // node_b2 [128]
    const float* pw = (const float*)d_in[22];  // pool_w  [3][128]
    float* out = (float*)d_out;

    float4* d4 = (float4*)d_ws;   // [65536] float4 = 1 MB

    k1_fused<<<256, 256, 0, stream>>>(x, W1, b1, W2, b2, pw, d4);
    k2_cascade<<<NGRAPH, 1024, 0, stream>>>(x, W1, b1, W2, b2, d4, out);
}